// Round 11
// baseline (190.690 us; speedup 1.0000x reference)
//
#include <hip/hip_runtime.h>
#include <math.h>

#define NB 8192
#define ND 512
#define NPROTO 16
#define GRID 256                   // one block per CU; all co-resident (33KB LDS)
#define TINV 14.285714285714286f   // 1/0.07
#define PLD (ND + 4)
#define SMEM_BYTES 33024           // max(acc 32K, gemm 24.9K, pl 33.0K)

typedef short short8 __attribute__((ext_vector_type(8)));
typedef float float4v __attribute__((ext_vector_type(4)));

__device__ __forceinline__ unsigned short f2bf(float f) {
  unsigned u = __builtin_bit_cast(unsigned, f);
  unsigned r = (u + 0x7FFFu + ((u >> 16) & 1u)) >> 16;
  return (unsigned short)r;
}
__device__ __forceinline__ float bflo(unsigned u) {
  return __builtin_bit_cast(float, u << 16);
}
__device__ __forceinline__ float bfhi(unsigned u) {
  return __builtin_bit_cast(float, u & 0xFFFF0000u);
}

// grid barrier: count+generation, self-resetting (replay-safe), bounded spin
__device__ __forceinline__ void gridBar(unsigned* cnt, unsigned* gen) {
  __syncthreads();
  if (threadIdx.x == 0) {
    __threadfence();                           // release prior writes
    const unsigned g = atomicAdd(gen, 0u);     // snapshot BEFORE arriving
    const unsigned old = atomicAdd(cnt, 1u);
    if (old == (unsigned)(GRID - 1)) {
      atomicExch(cnt, 0u);                     // reset for next barrier
      __threadfence();
      atomicAdd(gen, 1u);                      // release waiters
    } else {
      int spins = 0;
      while (atomicAdd(gen, 0u) == g) {
        __builtin_amdgcn_s_sleep(16);
        if (++spins > (1 << 22)) break;        // safety valve: fail, don't hang
      }
    }
    __threadfence();                           // acquire
  }
  __syncthreads();
}

__global__ __launch_bounds__(256) void k_all(
    const float* __restrict__ z, const float* __restrict__ attr,
    unsigned short* __restrict__ znb,
    float* __restrict__ partialSum,    // [16][256][512] f32 (8 MB)
    float* __restrict__ protos,        // [16][512]
    int* __restrict__ code, int* __restrict__ validList,
    int* __restrict__ validCnt,
    float* __restrict__ partialAll,    // [128][8192] (4 MB)
    float* __restrict__ partialPos,    // [128][8192] (4 MB)
    float* __restrict__ plPart,        // [256]
    float* __restrict__ rowLoss,       // [8192]
    unsigned* __restrict__ barCnt, unsigned* __restrict__ barGen,
    float* __restrict__ out)
{
  __shared__ __align__(16) char smem[SMEM_BYTES];
  __shared__ float red[8];
  __shared__ int lcnt;
  const int t = threadIdx.x, lane = t & 63, wid = t >> 6;
  const int bi = blockIdx.x;

  // ===== Phase 1: normalize + bf16 store + per-block segment partials =====
  {
    float* acc = (float*)smem;                 // [16][512]
    for (int i = t; i < NPROTO * ND; i += 256) acc[i] = 0.f;
    __syncthreads();
    #pragma unroll
    for (int rr = 0; rr < 8; ++rr) {
      const int r = bi * 32 + wid * 8 + rr;
      const float* zr = z + (size_t)r * ND;
      float v[8];
      #pragma unroll
      for (int jj = 0; jj < 8; ++jj) v[jj] = zr[lane + jj * 64];
      float s = 0.f;
      #pragma unroll
      for (int jj = 0; jj < 8; ++jj) s += v[jj] * v[jj];
      #pragma unroll
      for (int o = 32; o > 0; o >>= 1) s += __shfl_xor(s, o);
      const float inv = 1.f / fmaxf(sqrtf(s), 1e-12f);
      const float* a = attr + (size_t)r * 4;
      const int c = (a[0] > 0.5f ? 8 : 0) | (a[1] > 0.5f ? 4 : 0) |
                    (a[2] > 0.5f ? 2 : 0) | (a[3] > 0.5f ? 1 : 0);
      float* accRow = acc + c * ND;
      #pragma unroll
      for (int jj = 0; jj < 8; ++jj) {
        const float zv = v[jj] * inv;
        atomicAdd(&accRow[lane + jj * 64], zv);   // LDS, conflict-free
        znb[(size_t)r * ND + lane + jj * 64] = f2bf(zv);
      }
      if (lane == 0) code[r] = c;
    }
    __syncthreads();
    for (int i = t; i < NPROTO * ND; i += 256) {  // full overwrite, coalesced
      const int p = i >> 9, d = i & 511;
      partialSum[((size_t)p * GRID + bi) * ND + d] = acc[i];
    }
  }
  gridBar(barCnt, barGen);

  // ===== Phase 2: proto reduce+normalize (16 blocks); block15 valid list ===
  if (bi < NPROTO) {
    const int p = bi;
    if (t == 0) lcnt = 0;
    __syncthreads();
    const float* base = partialSum + (size_t)p * GRID * ND;
    float s0 = 0.f, s1 = 0.f;
    #pragma unroll 8
    for (int b = 0; b < GRID; ++b) {            // contiguous 512 KB per block
      s0 += base[b * ND + t];
      s1 += base[b * ND + t + 256];
    }
    float cl = 0.f;
    for (int r = t; r < NB; r += 256) {
      const int match = (code[r] == p) ? 1 : 0;
      cl += (float)match;
      if (p == NPROTO - 1 && match) {
        const int slot = atomicAdd(&lcnt, 1);
        validList[slot] = r;
      }
    }
    #pragma unroll
    for (int o = 32; o > 0; o >>= 1) cl += __shfl_xor(cl, o);
    if (lane == 0) red[wid] = cl;
    __syncthreads();
    const float cTot = red[0] + red[1] + red[2] + red[3];
    __syncthreads();
    const float invc = 1.f / fmaxf(cTot, 1.f);
    const float m0 = s0 * invc, m1 = s1 * invc;
    float sq = m0 * m0 + m1 * m1;
    #pragma unroll
    for (int o = 32; o > 0; o >>= 1) sq += __shfl_xor(sq, o);
    if (lane == 0) red[wid] = sq;
    __syncthreads();
    const float sum = red[0] + red[1] + red[2] + red[3];
    const float scale = (cTot > 0.f) ? 1.f / fmaxf(sqrtf(sum), 1e-12f) : 0.f;
    protos[p * ND + t] = m0 * scale;
    protos[p * ND + t + 256] = m1 * scale;
    if (p == NPROTO - 1 && t == 0) validCnt[0] = lcnt;
  }
  gridBar(barCnt, barGen);

  // ===== Phase 3a: pairwise MFMA GEMM (R9-verified loop, 2 items/block) ====
  const int m = validCnt[0];
  {
    unsigned short* aT = (unsigned short*)smem;             // 64x64, 8 KB
    unsigned short* bT = aT + 64 * 64;                      // 128x64, 16 KB
    int* rowIdx = (int*)(bT + 128 * 64);                    // 64
    unsigned char* aoSh = (unsigned char*)(rowIdx + 64);    // 128
    const int ww = wid & 1, wv = wid >> 1;
    const int nIT = (m + 63) >> 6;
    const int items = nIT * 64;
    const int grp = lane >> 4, cl = lane & 15;
    for (int wi = bi; wi < items; wi += GRID) {
      const int i0 = (wi >> 6) * 64;
      const int jt = wi & 63;
      const int jb = jt * 128;
      __syncthreads();
      if (t < 64) rowIdx[t] = (i0 + t < m) ? validList[i0 + t] : -1;
      if (t < 128) aoSh[t] = (code[jb + t] == NPROTO - 1) ? 1 : 0;
      float4v acc[2][4];
      #pragma unroll
      for (int mi = 0; mi < 2; ++mi)
        #pragma unroll
        for (int nj = 0; nj < 4; ++nj) acc[mi][nj] = (float4v)(0.f);
      for (int kc = 0; kc < 8; ++kc) {
        const int k0 = kc * 64;
        __syncthreads();
        {  // stage A: gathered via validList
          const int ia = t >> 2;
          const int ri = rowIdx[ia];
          const int srow = (ri < 0) ? 0 : ri;
          #pragma unroll
          for (int h = 0; h < 2; ++h) {
            const int kq = (t & 3) + h * 4;
            const uint4 v = *(const uint4*)(znb + (size_t)srow * ND + k0 + kq * 8);
            *(uint4*)((char*)aT + ia * 128 + ((kq * 16) ^ ((ia & 7) << 4))) = v;
          }
        }
        #pragma unroll
        for (int h = 0; h < 4; ++h) {  // stage B
          const int f = t + h * 256;
          const int j = f >> 3, kq = f & 7;
          const uint4 v = *(const uint4*)(znb + (size_t)(jb + j) * ND + k0 + kq * 8);
          *(uint4*)((char*)bT + j * 128 + ((kq * 16) ^ ((j & 7) << 4))) = v;
        }
        __syncthreads();
        #pragma unroll
        for (int ks = 0; ks < 2; ++ks) {
          const int kb = ks * 64 + grp * 16;
          short8 af[2], bf[4];
          #pragma unroll
          for (int mi = 0; mi < 2; ++mi) {
            const int rw = wv * 32 + mi * 16 + cl;
            af[mi] = *(const short8*)((char*)aT + rw * 128 + (kb ^ ((rw & 7) << 4)));
          }
          #pragma unroll
          for (int nj = 0; nj < 4; ++nj) {
            const int rw = ww * 64 + nj * 16 + cl;
            bf[nj] = *(const short8*)((char*)bT + rw * 128 + (kb ^ ((rw & 7) << 4)));
          }
          #pragma unroll
          for (int mi = 0; mi < 2; ++mi)
            #pragma unroll
            for (int nj = 0; nj < 4; ++nj)
              acc[mi][nj] = __builtin_amdgcn_mfma_f32_16x16x32_bf16(af[mi], bf[nj], acc[mi][nj], 0, 0, 0);
        }
      }
      #pragma unroll
      for (int mi = 0; mi < 2; ++mi) {
        float sA[4] = {0.f, 0.f, 0.f, 0.f}, sP[4] = {0.f, 0.f, 0.f, 0.f};
        int ri[4];
        #pragma unroll
        for (int q = 0; q < 4; ++q) ri[q] = rowIdx[wv * 32 + mi * 16 + grp * 4 + q];
        #pragma unroll
        for (int nj = 0; nj < 4; ++nj) {
          const int jl = ww * 64 + nj * 16 + cl;
          const int jg = jb + jl;
          const float ao = aoSh[jl] ? 1.f : 0.f;
          #pragma unroll
          for (int q = 0; q < 4; ++q) {
            float e = __expf(acc[mi][nj][q] * TINV);
            e = (jg == ri[q]) ? 0.f : e;
            sA[q] += e;
            sP[q] += e * ao;
          }
        }
        #pragma unroll
        for (int q = 0; q < 4; ++q) {
          #pragma unroll
          for (int o = 1; o < 16; o <<= 1) {
            sA[q] += __shfl_xor(sA[q], o);
            sP[q] += __shfl_xor(sP[q], o);
          }
        }
        if (cl == 0) {
          const int slot0 = i0 + wv * 32 + mi * 16 + grp * 4;
          const int jt2 = jt * 2 + ww;
          if (slot0 + 3 < m) {
            *(float4*)&partialAll[(size_t)jt2 * NB + slot0] =
                make_float4(sA[0], sA[1], sA[2], sA[3]);
            *(float4*)&partialPos[(size_t)jt2 * NB + slot0] =
                make_float4(sP[0], sP[1], sP[2], sP[3]);
          } else {
            #pragma unroll
            for (int q = 0; q < 4; ++q) {
              if (slot0 + q < m) {
                partialAll[(size_t)jt2 * NB + slot0 + q] = sA[q];
                partialPos[(size_t)jt2 * NB + slot0 + q] = sP[q];
              }
            }
          }
        }
      }
    }
  }
  __syncthreads();

  // ===== Phase 3b: protoloss (all 256 blocks, 32 rows each) ===============
  {
    float* pl = (float*)smem;                               // [16][PLD]
    for (int i = t; i < NPROTO * ND; i += 256)
      pl[(i >> 9) * PLD + (i & 511)] = protos[i];
    __syncthreads();
    const int p = lane & 15, grp = lane >> 4;
    float lacc = 0.f;
    #pragma unroll
    for (int it8 = 0; it8 < 8; ++it8) {
      const int r = bi * 4 + wid + it8 * 1024;
      const uint4* zr = (const uint4*)(znb + (size_t)r * ND + grp * 128);
      const float* pbp = &pl[p * PLD + grp * 128];
      float s = 0.f;
      #pragma unroll
      for (int it = 0; it < 16; ++it) {
        const uint4 u = zr[it];
        const float4 p0 = *(const float4*)(pbp + it * 8);
        const float4 p1 = *(const float4*)(pbp + it * 8 + 4);
        s += bflo(u.x)*p0.x + bfhi(u.x)*p0.y + bflo(u.y)*p0.z + bfhi(u.y)*p0.w;
        s += bflo(u.z)*p1.x + bfhi(u.z)*p1.y + bflo(u.w)*p1.z + bfhi(u.w)*p1.w;
      }
      s += __shfl_xor(s, 16);
      s += __shfl_xor(s, 32);
      const float e = __expf(s * TINV);
      float alls = e;
      alls += __shfl_xor(alls, 1);
      alls += __shfl_xor(alls, 2);
      alls += __shfl_xor(alls, 4);
      alls += __shfl_xor(alls, 8);
      const int c = code[r];
      const float pos = __shfl(e, (lane & ~15) | c);
      if (lane == 0) lacc += -logf(pos / fmaxf(alls, 1e-8f) + 1e-8f);
    }
    if (lane == 0) red[wid] = lacc;
    __syncthreads();
    if (t == 0) plPart[bi] = red[0] + red[1] + red[2] + red[3];
  }
  gridBar(barCnt, barGen);

  // ===== Phase 4: column-reduce partials -> rowLoss =======================
  {
    float* sh = (float*)smem;                  // [256]
    for (int s = bi; s < m; s += GRID) {
      float v = 0.f;
      if (t < 128) v = partialAll[(size_t)t * NB + s];
      else         v = partialPos[(size_t)(t - 128) * NB + s];
      #pragma unroll
      for (int o = 32; o > 0; o >>= 1) v += __shfl_xor(v, o);
      if (lane == 0) sh[wid] = v;
      __syncthreads();
      if (t == 0) {
        const float A = sh[0] + sh[1];
        const float P = sh[2] + sh[3];
        rowLoss[s] = -logf(P / (A + 1e-8f) + 1e-8f);
      }
      __syncthreads();
    }
  }
  gridBar(barCnt, barGen);

  // ===== Phase 5: finalize (block 0) ======================================
  if (bi == 0) {
    const int nvalid = (m >= 2) ? m : 0;
    float s = 0.f;
    for (int i = t; i < nvalid; i += 256) s += rowLoss[i];
    float pls = plPart[t];
    #pragma unroll
    for (int o = 32; o > 0; o >>= 1) {
      s += __shfl_xor(s, o);
      pls += __shfl_xor(pls, o);
    }
    if (lane == 0) { red[wid] = s; red[4 + wid] = pls; }
    __syncthreads();
    if (t == 0) {
      const float total = red[0] + red[1] + red[2] + red[3];
      const float plTot = red[4] + red[5] + red[6] + red[7];
      const float proto = plTot / (float)NB;
      float loss = proto;
      if (nvalid > 0) loss = 0.7f * proto + 0.3f * (total / (float)nvalid);
      out[0] = loss;
    }
  }
}

extern "C" void kernel_launch(void* const* d_in, const int* in_sizes, int n_in,
                              void* d_out, int out_size, void* d_ws, size_t ws_size,
                              hipStream_t stream) {
  const float* z = (const float*)d_in[0];
  const float* attr = (const float*)d_in[1];
  char* w = (char*)d_ws;
  unsigned short* znb = (unsigned short*)w;  w += (size_t)NB * ND * 2;       // 8 MB
  float* partialSum = (float*)w;             w += (size_t)NPROTO * GRID * ND * 4; // 8 MB
  float* partialAll = (float*)w;             w += (size_t)128 * NB * 4;      // 4 MB
  float* partialPos = (float*)w;             w += (size_t)128 * NB * 4;      // 4 MB
  float* protos = (float*)w;                 w += NPROTO * ND * 4;
  int* code = (int*)w;                       w += NB * 4;
  int* validList = (int*)w;                  w += NB * 4;
  int* validCnt = (int*)w;                   w += 16;
  float* plPart = (float*)w;                 w += GRID * 4;
  float* rowLoss = (float*)w;                w += NB * 4;
  unsigned* barCnt = (unsigned*)w;           w += 16;   // {cnt, gen} zeroed below
  unsigned* barGen = barCnt + 1;
  float* outp = (float*)d_out;
  hipMemsetAsync(barCnt, 0, 8, stream);
  k_all<<<dim3(GRID), dim3(256), 0, stream>>>(
      z, attr, znb, partialSum, protos, code, validList, validCnt,
      partialAll, partialPos, plPart, rowLoss, barCnt, barGen, outp);
}

// Round 12
// 68.664 us; speedup vs baseline: 2.7772x; 2.7772x over previous
//
#include <hip/hip_runtime.h>
#include <math.h>

#define NB 8192
#define ND 512
#define NPROTO 16
#define NBLK 256                   // k_norm grid
#define TINV 14.285714285714286f   // 1/0.07
#define PW_BLOCKS 256
#define PL_BLOCKS 256

typedef short short8 __attribute__((ext_vector_type(8)));
typedef float float4v __attribute__((ext_vector_type(4)));

__device__ __forceinline__ unsigned short f2bf(float f) {
  unsigned u = __builtin_bit_cast(unsigned, f);
  unsigned r = (u + 0x7FFFu + ((u >> 16) & 1u)) >> 16;
  return (unsigned short)r;
}
__device__ __forceinline__ float bflo(unsigned u) {
  return __builtin_bit_cast(float, u << 16);
}
__device__ __forceinline__ float bfhi(unsigned u) {
  return __builtin_bit_cast(float, u & 0xFFFF0000u);
}

// ---- K1: wave-per-row normalize + bf16 store + non-atomic partial sums ----
// partialSum layout: [p][block][d]
__global__ __launch_bounds__(512) void k_norm(
    const float* __restrict__ z, const float* __restrict__ attr,
    unsigned short* __restrict__ znb, float* __restrict__ partialSum,
    int* __restrict__ code)
{
  __shared__ float acc[NPROTO * ND];   // 32 KB
  const int t = threadIdx.x, lane = t & 63, wid = t >> 6;
  for (int i = t; i < NPROTO * ND; i += 512) acc[i] = 0.f;
  __syncthreads();
  #pragma unroll
  for (int rr = 0; rr < 4; ++rr) {
    const int r = blockIdx.x * 32 + wid * 4 + rr;
    const float* zr = z + (size_t)r * ND;
    float v[8];
    #pragma unroll
    for (int jj = 0; jj < 8; ++jj) v[jj] = zr[lane + jj * 64];
    float s = 0.f;
    #pragma unroll
    for (int jj = 0; jj < 8; ++jj) s += v[jj] * v[jj];
    #pragma unroll
    for (int o = 32; o > 0; o >>= 1) s += __shfl_xor(s, o);
    const float inv = 1.f / fmaxf(sqrtf(s), 1e-12f);
    const float* a = attr + (size_t)r * 4;
    const int c = (a[0] > 0.5f ? 8 : 0) | (a[1] > 0.5f ? 4 : 0) |
                  (a[2] > 0.5f ? 2 : 0) | (a[3] > 0.5f ? 1 : 0);
    float* accRow = acc + c * ND;
    #pragma unroll
    for (int jj = 0; jj < 8; ++jj) {
      const float zv = v[jj] * inv;
      atomicAdd(&accRow[lane + jj * 64], zv);        // LDS, consecutive banks
      znb[(size_t)r * ND + lane + jj * 64] = f2bf(zv);
    }
    if (lane == 0) code[r] = c;
  }
  __syncthreads();
  for (int i = t; i < NPROTO * ND; i += 512) {      // full overwrite: no pre-zero
    const int p = i >> 9, d = i & 511;
    partialSum[(size_t)((p << 8) | blockIdx.x) * ND + d] = acc[i];
  }
}

// ---- K1b: stage-1 reduce: 256 blocks, (p,c) sums 16 partials --------------
__global__ __launch_bounds__(256) void k_reduce1(
    const float* __restrict__ partialSum, float* __restrict__ partial2)
{
  const int t = threadIdx.x;
  const int p = blockIdx.x >> 4, c = blockIdx.x & 15;
  const float* base = partialSum + (size_t)(p * NBLK + c * 16) * ND;
  float s0 = 0.f, s1 = 0.f;
  #pragma unroll
  for (int k = 0; k < 16; ++k) {
    s0 += base[k * ND + t];
    s1 += base[k * ND + t + 256];
  }
  partial2[(size_t)(p * 16 + c) * ND + t] = s0;
  partial2[(size_t)(p * 16 + c) * ND + t + 256] = s1;
}

// ---- K2: 16 blocks: final reduce (32KB each) + normalize + validList ------
__global__ __launch_bounds__(512) void k_protonorm(
    const float* __restrict__ partial2, const int* __restrict__ code,
    float* __restrict__ protos, int* __restrict__ validList,
    int* __restrict__ validCnt)
{
  __shared__ float red[8];
  __shared__ int lcnt;
  const int t = threadIdx.x, lane = t & 63, wid = t >> 6;
  const int p = blockIdx.x;
  if (t == 0) lcnt = 0;
  __syncthreads();
  const float* base = partial2 + (size_t)p * 16 * ND;
  float s = 0.f;
  #pragma unroll
  for (int c = 0; c < 16; ++c)
    s += base[c * ND + t];
  float cl = 0.f;
  for (int r = t; r < NB; r += 512) {
    const int match = (code[r] == p) ? 1 : 0;
    cl += (float)match;
    if (p == NPROTO - 1 && match) {
      const int slot = atomicAdd(&lcnt, 1);
      validList[slot] = r;
    }
  }
  #pragma unroll
  for (int o = 32; o > 0; o >>= 1) cl += __shfl_xor(cl, o);
  if (lane == 0) red[wid] = cl;
  __syncthreads();
  const float cTot = red[0]+red[1]+red[2]+red[3]+red[4]+red[5]+red[6]+red[7];
  __syncthreads();
  const float mean = s / fmaxf(cTot, 1.f);
  float sq = mean * mean;
  #pragma unroll
  for (int o = 32; o > 0; o >>= 1) sq += __shfl_xor(sq, o);
  if (lane == 0) red[wid] = sq;
  __syncthreads();
  const float sum = red[0]+red[1]+red[2]+red[3]+red[4]+red[5]+red[6]+red[7];
  const float scale = (cTot > 0.f) ? 1.f / fmaxf(sqrtf(sum), 1e-12f) : 0.f;
  protos[p * ND + t] = mean * scale;
  if (p == NPROTO - 1 && t == 0) validCnt[0] = lcnt;
}

// ---- K3: fused {pairwise MFMA GEMM (512thr, 64x256 tile) | protoloss} -----
#define PLD (ND + 4)
#define SMEM_BYTES 41472
__global__ __launch_bounds__(512) void k_main(
    const unsigned short* __restrict__ znb, const float* __restrict__ protos,
    const int* __restrict__ code, const int* __restrict__ validList,
    const int* __restrict__ validCnt,
    float* __restrict__ partialAll, float* __restrict__ partialPos,
    float* __restrict__ plPart)
{
  __shared__ __align__(16) char smem[SMEM_BYTES];
  __shared__ float red3[8];
  const int t = threadIdx.x, lane = t & 63, wid = t >> 6;
  const int bi = blockIdx.x;
  if (bi < PW_BLOCKS) {
    // -------- pairwise: 8 waves (2i x 4j), tile 64i x 256j, K-chunk 64 ----
    unsigned short* aT = (unsigned short*)smem;             // 64x64, 8 KB
    unsigned short* bT = aT + 64 * 64;                      // 256x64, 32 KB
    int* rowIdx = (int*)(bT + 256 * 64);                    // 64
    unsigned char* aoSh = (unsigned char*)(rowIdx + 64);    // 256
    const int wv = wid >> 2, ww = wid & 3;
    const int m = validCnt[0];
    const int nIT = (m + 63) >> 6;
    const int items = nIT * 32;                             // 32 j-tiles of 256
    const int grp = lane >> 4, cl = lane & 15;
    for (int wi = bi; wi < items; wi += PW_BLOCKS) {
      const int i0 = (wi >> 5) * 64;
      const int jt = wi & 31;
      const int jb = jt * 256;
      __syncthreads();
      if (t < 64) rowIdx[t] = (i0 + t < m) ? validList[i0 + t] : -1;
      if (t < 256) aoSh[t] = (code[jb + t] == NPROTO - 1) ? 1 : 0;
      float4v acc[2][4];
      #pragma unroll
      for (int mi = 0; mi < 2; ++mi)
        #pragma unroll
        for (int nj = 0; nj < 4; ++nj) acc[mi][nj] = (float4v)(0.f);
      for (int kc = 0; kc < 8; ++kc) {
        const int k0 = kc * 64;
        __syncthreads();
        {  // stage A: 64 rows x 8 chunks = 512, 1/thread
          const int ia = t >> 3, kq = t & 7;
          const int ri = rowIdx[ia];
          const int srow = (ri < 0) ? 0 : ri;
          const uint4 v = *(const uint4*)(znb + (size_t)srow * ND + k0 + kq * 8);
          *(uint4*)((char*)aT + ia * 128 + ((kq * 16) ^ ((ia & 7) << 4))) = v;
        }
        #pragma unroll
        for (int h = 0; h < 4; ++h) {  // stage B: 256 rows x 8 chunks, 4/thread
          const int f = t + h * 512;
          const int j = f >> 3, kq = f & 7;
          const uint4 v = *(const uint4*)(znb + (size_t)(jb + j) * ND + k0 + kq * 8);
          *(uint4*)((char*)bT + j * 128 + ((kq * 16) ^ ((j & 7) << 4))) = v;
        }
        __syncthreads();
        #pragma unroll
        for (int ks = 0; ks < 2; ++ks) {
          const int kb = ks * 64 + grp * 16;
          short8 af[2], bf[4];
          #pragma unroll
          for (int mi = 0; mi < 2; ++mi) {
            const int rw = wv * 32 + mi * 16 + cl;
            af[mi] = *(const short8*)((char*)aT + rw * 128 + (kb ^ ((rw & 7) << 4)));
          }
          #pragma unroll
          for (int nj = 0; nj < 4; ++nj) {
            const int rw = ww * 64 + nj * 16 + cl;
            bf[nj] = *(const short8*)((char*)bT + rw * 128 + (kb ^ ((rw & 7) << 4)));
          }
          #pragma unroll
          for (int mi = 0; mi < 2; ++mi)
            #pragma unroll
            for (int nj = 0; nj < 4; ++nj)
              acc[mi][nj] = __builtin_amdgcn_mfma_f32_16x16x32_bf16(af[mi], bf[nj], acc[mi][nj], 0, 0, 0);
        }
      }
      // epilogue: exp, diag+pos masks, row sums, direct partial writes
      #pragma unroll
      for (int mi = 0; mi < 2; ++mi) {
        float sA[4] = {0.f, 0.f, 0.f, 0.f}, sP[4] = {0.f, 0.f, 0.f, 0.f};
        int ri[4];
        #pragma unroll
        for (int q = 0; q < 4; ++q) ri[q] = rowIdx[wv * 32 + mi * 16 + grp * 4 + q];
        #pragma unroll
        for (int nj = 0; nj < 4; ++nj) {
          const int jl = ww * 64 + nj * 16 + cl;
          const int jg = jb + jl;
          const float ao = aoSh[jl] ? 1.f : 0.f;
          #pragma unroll
          for (int q = 0; q < 4; ++q) {
            float e = __expf(acc[mi][nj][q] * TINV);
            e = (jg == ri[q]) ? 0.f : e;
            sA[q] += e;
            sP[q] += e * ao;
          }
        }
        #pragma unroll
        for (int q = 0; q < 4; ++q) {
          #pragma unroll
          for (int o = 1; o < 16; o <<= 1) {
            sA[q] += __shfl_xor(sA[q], o);
            sP[q] += __shfl_xor(sP[q], o);
          }
        }
        if (cl == 0) {
          const int slot0 = i0 + wv * 32 + mi * 16 + grp * 4;
          const int jt2 = jt * 4 + ww;                      // 0..127
          if (slot0 + 3 < m) {
            *(float4*)&partialAll[(size_t)jt2 * NB + slot0] =
                make_float4(sA[0], sA[1], sA[2], sA[3]);
            *(float4*)&partialPos[(size_t)jt2 * NB + slot0] =
                make_float4(sP[0], sP[1], sP[2], sP[3]);
          } else {
            #pragma unroll
            for (int q = 0; q < 4; ++q) {
              if (slot0 + q < m) {
                partialAll[(size_t)jt2 * NB + slot0 + q] = sA[q];
                partialPos[(size_t)jt2 * NB + slot0 + q] = sP[q];
              }
            }
          }
        }
      }
    }
  } else {
    // -------- protoloss: 256 blocks x 512 thr, 32 rows each ---------------
    float* pl = (float*)smem;                               // [16][PLD]
    const int pb = bi - PW_BLOCKS;
    for (int i = t; i < NPROTO * ND; i += 512)
      pl[(i >> 9) * PLD + (i & 511)] = protos[i];
    __syncthreads();
    const int p = lane & 15, grp = lane >> 4;
    float lacc = 0.f;
    #pragma unroll
    for (int rr = 0; rr < 4; ++rr) {
      const int r = pb * 32 + wid * 4 + rr;
      const uint4* zr = (const uint4*)(znb + (size_t)r * ND + grp * 128);
      const float* pbp = &pl[p * PLD + grp * 128];
      float s = 0.f;
      #pragma unroll
      for (int it = 0; it < 16; ++it) {
        const uint4 u = zr[it];
        const float4 p0 = *(const float4*)(pbp + it * 8);
        const float4 p1 = *(const float4*)(pbp + it * 8 + 4);
        s += bflo(u.x)*p0.x + bfhi(u.x)*p0.y + bflo(u.y)*p0.z + bfhi(u.y)*p0.w;
        s += bflo(u.z)*p1.x + bfhi(u.z)*p1.y + bflo(u.w)*p1.z + bfhi(u.w)*p1.w;
      }
      s += __shfl_xor(s, 16);
      s += __shfl_xor(s, 32);
      const float e = __expf(s * TINV);
      float alls = e;
      alls += __shfl_xor(alls, 1);
      alls += __shfl_xor(alls, 2);
      alls += __shfl_xor(alls, 4);
      alls += __shfl_xor(alls, 8);
      const int c = code[r];
      const float pos = __shfl(e, (lane & ~15) | c);
      if (lane == 0) lacc += -logf(pos / fmaxf(alls, 1e-8f) + 1e-8f);
    }
    if (lane == 0) red3[wid] = lacc;
    __syncthreads();
    if (t == 0)
      plPart[pb] = red3[0]+red3[1]+red3[2]+red3[3]+red3[4]+red3[5]+red3[6]+red3[7];
  }
}

// ---- K4: finalize — 1024 thr, coalesced column reads, split-k halves ------
__global__ __launch_bounds__(1024) void k_final(
    const float* __restrict__ partialAll, const float* __restrict__ partialPos,
    const float* __restrict__ plPart, const int* __restrict__ validCnt,
    float* __restrict__ out)
{
  __shared__ float shA[1024], shP[1024];
  __shared__ float red[16], red2[16];
  const int t = threadIdx.x, lane = t & 63, wid = t >> 6;
  const int m = validCnt[0];
  const int nvalid = (m >= 2) ? m : 0;
  const int slot = t & 511, half = t >> 9;
  float sa = 0.f, sp = 0.f;
  if (slot < nvalid) {
    const int k0 = half * 64;
    #pragma unroll 8
    for (int k = k0; k < k0 + 64; ++k) {
      sa += partialAll[(size_t)k * NB + slot];   // coalesced across threads
      sp += partialPos[(size_t)k * NB + slot];
    }
  }
  shA[t] = sa; shP[t] = sp;
  __syncthreads();
  float s = 0.f;
  if (t < 512 && slot < nvalid) {
    const float A = shA[t] + shA[t + 512];
    const float P = shP[t] + shP[t + 512];
    s = -logf(P / (A + 1e-8f) + 1e-8f);
  }
  float pls = (t < PL_BLOCKS) ? plPart[t] : 0.f;
  #pragma unroll
  for (int o = 32; o > 0; o >>= 1) {
    s += __shfl_xor(s, o);
    pls += __shfl_xor(pls, o);
  }
  if (lane == 0) { red[wid] = s; red2[wid] = pls; }
  __syncthreads();
  if (t == 0) {
    float total = 0.f, plTot = 0.f;
    #pragma unroll
    for (int w = 0; w < 16; ++w) { total += red[w]; plTot += red2[w]; }
    const float proto = plTot / (float)NB;
    float loss = proto;
    if (nvalid > 0) loss = 0.7f * proto + 0.3f * (total / (float)nvalid);
    out[0] = loss;
  }
}

extern "C" void kernel_launch(void* const* d_in, const int* in_sizes, int n_in,
                              void* d_out, int out_size, void* d_ws, size_t ws_size,
                              hipStream_t stream) {
  const float* z = (const float*)d_in[0];
  const float* attr = (const float*)d_in[1];
  unsigned short* znb = (unsigned short*)d_ws;            // NB*ND bf16 (8 MB)
  float* partialSum = (float*)(znb + (size_t)NB * ND);    // [p][b][d] (8 MB)
  // overlay: partialSum is dead after k_reduce1/protonorm; k_main reuses it
  float* partialAll = partialSum;                         // [128][NB] (4 MB)
  float* partialPos = partialSum + (size_t)128 * NB;      // [128][NB] (4 MB)
  char* w = (char*)(partialSum + (size_t)NBLK * NPROTO * ND);
  float* partial2 = (float*)w;      w += (size_t)NPROTO * 16 * ND * 4;  // 512 KB
  int* validCnt = (int*)w;          w += 16;
  int* code = (int*)w;              w += NB * 4;
  int* validList = (int*)w;         w += NB * 4;
  float* protos = (float*)w;        w += NPROTO * ND * 4;
  float* plPart = (float*)w;        w += PL_BLOCKS * 4;
  k_norm<<<dim3(NBLK), dim3(512), 0, stream>>>(z, attr, znb, partialSum, code);
  k_reduce1<<<dim3(256), dim3(256), 0, stream>>>(partialSum, partial2);
  k_protonorm<<<dim3(NPROTO), dim3(512), 0, stream>>>(partial2, code, protos,
                                                      validList, validCnt);
  k_main<<<dim3(PW_BLOCKS + PL_BLOCKS), dim3(512), 0, stream>>>(
      znb, protos, code, validList, validCnt, partialAll, partialPos, plPart);
  k_final<<<dim3(1), dim3(1024), 0, stream>>>(partialAll, partialPos, plPart,
                                              validCnt, (float*)d_out);
}